// Round 14
// baseline (195.815 us; speedup 1.0000x reference)
//
#include <hip/hip_runtime.h>
#include <hip/hip_bf16.h>
#include <math.h>

// DIAGNOSTIC ROUND: R12 kernel + 4 phase-ablation probes (write to d_ws,
// keep-alive sinks). Real kernel (MODE=15) runs last, writes d_out — output
// identical to R12. rocprof per-dispatch dur_us localizes the phase costs.
// MODE bits: 1=stage, 2=QK^T, 4=softmax(mask+exp2+pack+permlane), 8=PV.

constexpr int Bn = 4, Ln = 2048, Hn = 8, En = 64;
constexpr int QBLK = 128;
constexpr int KVBLK = 128;

using f32x4  = __attribute__((ext_vector_type(4))) float;
using f32x16 = __attribute__((ext_vector_type(16))) float;
using bf16x8 = __attribute__((ext_vector_type(8))) short;
using u32x4  = __attribute__((ext_vector_type(4))) unsigned int;

#define SCALE_LOG2E 0.1803368801111204f

__device__ inline short2 cvt2(float a, float b) {
  __hip_bfloat162 h = __float22bfloat162_rn(make_float2(a, b));
  return *reinterpret_cast<short2*>(&h);
}
__device__ inline unsigned pack2(float a, float b) {
  short2 s = cvt2(a, b);
  return *reinterpret_cast<unsigned*>(&s);
}
__device__ inline bf16x8 cvt8(f32x4 a, f32x4 b) {
  short2 p0 = cvt2(a[0], a[1]), p1 = cvt2(a[2], a[3]);
  short2 p2 = cvt2(b[0], b[1]), p3 = cvt2(b[2], b[3]);
  bf16x8 v;
  v[0] = p0.x; v[1] = p0.y; v[2] = p1.x; v[3] = p1.y;
  v[4] = p2.x; v[5] = p2.y; v[6] = p3.x; v[7] = p3.y;
  return v;
}

template<int MODE, bool REAL>
__global__ __launch_bounds__(256, 2)
void attn_k(const float* __restrict__ Qg, const float* __restrict__ Kg,
            const float* __restrict__ Vg, float* __restrict__ Og) {
  constexpr bool DO_STAGE = (MODE & 1) != 0;
  constexpr bool DO_QKT   = (MODE & 2) != 0;
  constexpr bool DO_SM    = (MODE & 4) != 0;
  constexpr bool DO_PV    = (MODE & 8) != 0;

  const int wg   = blockIdx.x;
  const int pp   = wg >> 5;
  const int qb   = (pp < 8) ? (15 - pp) : (pp - 8);
  const int bh   = wg & 31;
  const int b    = bh >> 3;
  const int h    = bh & 7;
  const int tid  = threadIdx.x;
  const int lane = tid & 63;
  const int wave = tid >> 6;
  const int q32  = lane & 31;
  const int hh   = lane >> 5;

  __shared__ __align__(16) short Klds[2][KVBLK][72];
  __shared__ __align__(16) short Vtld[2][En][136];

  const size_t base = ((size_t)b * Ln * Hn + (size_t)h) * En;
  const int rowstride = Hn * En;
  const int qbase = qb * QBLK + wave * 32;
  const int q     = qbase + q32;

  bf16x8 qf[4];
  {
    const float* qp = Qg + base + (size_t)q * rowstride + hh * 8;
#pragma unroll
    for (int m = 0; m < 4; ++m) {
      f32x4 a = *(const f32x4*)(qp + 16 * m);
      f32x4 c = *(const f32x4*)(qp + 16 * m + 4);
#pragma unroll
      for (int i = 0; i < 4; ++i) { a[i] *= SCALE_LOG2E; c[i] *= SCALE_LOG2E; }
      qf[m] = cvt8(a, c);
    }
  }

#define ZERO16 {0.f,0.f,0.f,0.f,0.f,0.f,0.f,0.f,0.f,0.f,0.f,0.f,0.f,0.f,0.f,0.f}
  f32x16 acc0 = ZERO16, acc1 = ZERO16, accl = ZERO16;
  const short oneb = (short)0x3F80;
  const bf16x8 ones = {oneb, oneb, oneb, oneb, oneb, oneb, oneb, oneb};
  const bf16x8 zfr  = {0, 0, 0, 0, 0, 0, 0, 0};
  float sinkf = 0.f;
  unsigned usink = 0u;

  const int ntiles = qb + 1;
  const int kr = tid >> 3;
  const int kc = (tid & 7) << 3;
  const int vkv = (tid & 31) << 1;
  const int vdd = (tid >> 5) << 3;
  const int vsw = ((vdd >> 3) & 7) << 3;

  const float* kbase = Kg + base;
  const float* vbase = Vg + base;
  f32x4 kx[8], vx[8];

#define LOAD_TILE(TB)                                                     \
  {                                                                       \
    _Pragma("unroll")                                                     \
    for (int u = 0; u < 4; ++u) {                                         \
      const float* kp = kbase + (size_t)((TB) + kr + 32 * u) * rowstride + kc; \
      kx[2 * u] = *(const f32x4*)kp; kx[2 * u + 1] = *(const f32x4*)(kp + 4);  \
    }                                                                     \
    const float* vp = vbase + (size_t)((TB) + vkv) * rowstride + vdd;     \
    vx[0] = *(const f32x4*)vp;  vx[1] = *(const f32x4*)(vp + 4);          \
    vx[2] = *(const f32x4*)(vp + rowstride);                              \
    vx[3] = *(const f32x4*)(vp + rowstride + 4);                          \
    const float* vq = vp + 64 * rowstride;                                \
    vx[4] = *(const f32x4*)vq;  vx[5] = *(const f32x4*)(vq + 4);          \
    vx[6] = *(const f32x4*)(vq + rowstride);                              \
    vx[7] = *(const f32x4*)(vq + rowstride + 4);                          \
  }

#define WRITE_TILE(BUF)                                                   \
  {                                                                       \
    _Pragma("unroll")                                                     \
    for (int u = 0; u < 4; ++u) {                                         \
      const int krw = kr + 32 * u;                                        \
      *(bf16x8*)&Klds[BUF][krw][kc ^ (((krw >> 3) & 7) << 3)] =           \
          cvt8(kx[2 * u], kx[2 * u + 1]);                                 \
    }                                                                     \
    _Pragma("unroll")                                                     \
    for (int k = 0; k < 4; ++k) {                                         \
      *(unsigned*)&Vtld[BUF][vdd + k][vkv ^ vsw]     = pack2(vx[0][k], vx[2][k]); \
      *(unsigned*)&Vtld[BUF][vdd + 4 + k][vkv ^ vsw] = pack2(vx[1][k], vx[3][k]); \
      *(unsigned*)&Vtld[BUF][vdd + k][(vkv + 64) ^ vsw]     = pack2(vx[4][k], vx[6][k]); \
      *(unsigned*)&Vtld[BUF][vdd + 4 + k][(vkv + 64) ^ vsw] = pack2(vx[5][k], vx[7][k]); \
    }                                                                     \
  }

  if constexpr (DO_STAGE) {
    LOAD_TILE(0)
    WRITE_TILE(0)
    if (ntiles > 1) LOAD_TILE(KVBLK)
  }

  for (int t = 0; t < ntiles; ++t) {
    const int cur = t & 1;
    __syncthreads();
    if constexpr (DO_STAGE) {
      if (t + 1 < ntiles) {
        WRITE_TILE(cur ^ 1)
        if (t + 2 < ntiles) LOAD_TILE((t + 2) * KVBLK)
      }
    }

    if constexpr (DO_QKT) {
      const int tb = t * KVBLK;
      const bool diag = (t == qb);

      bf16x8 pa[8];
#pragma unroll
      for (int sub = 0; sub < 4; ++sub) {
        if (diag && sub > wave) {
          if constexpr (DO_PV) { pa[2 * sub] = zfr; pa[2 * sub + 1] = zfr; }
          continue;
        }
        const int krow = sub * 32 + q32;
        const int ksw  = ((krow >> 3) & 7) << 3;
        f32x16 s = ZERO16;
        __builtin_amdgcn_s_setprio(1);
#pragma unroll
        for (int m = 0; m < 4; ++m) {
          bf16x8 kf = *(const bf16x8*)&Klds[cur][krow][(m * 16 + hh * 8) ^ ksw];
          s = __builtin_amdgcn_mfma_f32_32x32x16_bf16(kf, qf[m], s, 0, 0, 0);
        }
        __builtin_amdgcn_s_setprio(0);

        if constexpr (!DO_SM) {
          // keep-alive: consume raw scores, skip softmax/pack/PV feed
#pragma unroll
          for (int r = 0; r < 16; ++r) sinkf += s[r];
          continue;
        } else {
          if (diag && sub == wave) {
#pragma unroll
            for (int r = 0; r < 16; ++r) {
              const int kv = tb + sub * 32 + (r & 3) + 8 * (r >> 2) + 4 * hh;
              s[r] = (kv > q) ? 0.f : exp2f(s[r]);
            }
          } else {
#pragma unroll
            for (int r = 0; r < 16; ++r) s[r] = exp2f(s[r]);
          }
          unsigned w0 = pack2(s[0], s[1]),   w1 = pack2(s[2], s[3]);
          unsigned w2 = pack2(s[4], s[5]),   w3 = pack2(s[6], s[7]);
          unsigned w4 = pack2(s[8], s[9]),   w5 = pack2(s[10], s[11]);
          unsigned w6 = pack2(s[12], s[13]), w7 = pack2(s[14], s[15]);
          asm("v_permlane32_swap_b32 %0, %1" : "+v"(w0), "+v"(w2));
          asm("v_permlane32_swap_b32 %0, %1" : "+v"(w1), "+v"(w3));
          asm("v_permlane32_swap_b32 %0, %1" : "+v"(w4), "+v"(w6));
          asm("v_permlane32_swap_b32 %0, %1" : "+v"(w5), "+v"(w7));
          if constexpr (!DO_PV) {
            usink += w0 + w1 + w2 + w3 + w4 + w5 + w6 + w7;  // keep-alive
          } else {
            u32x4 Wa = {w0, w1, w2, w3};
            u32x4 Wb = {w4, w5, w6, w7};
            pa[2 * sub + 0] = __builtin_bit_cast(bf16x8, Wa);
            pa[2 * sub + 1] = __builtin_bit_cast(bf16x8, Wb);
          }
        }
      }

      if constexpr (DO_PV) {
        const int vswA = ((q32 >> 3) & 7) << 3;
        const int vswB = (((q32 >> 3) + 4) & 7) << 3;
        __builtin_amdgcn_s_setprio(1);
#pragma unroll
        for (int m = 0; m < 8; ++m) {
          bf16x8 vf0 = *(const bf16x8*)&Vtld[cur][q32][(m * 16 + hh * 8) ^ vswA];
          acc0 = __builtin_amdgcn_mfma_f32_32x32x16_bf16(pa[m], vf0, acc0, 0, 0, 0);
          bf16x8 vf1 = *(const bf16x8*)&Vtld[cur][q32 + 32][(m * 16 + hh * 8) ^ vswB];
          acc1 = __builtin_amdgcn_mfma_f32_32x32x16_bf16(pa[m], vf1, acc1, 0, 0, 0);
          accl = __builtin_amdgcn_mfma_f32_32x32x16_bf16(pa[m], ones, accl, 0, 0, 0);
        }
        __builtin_amdgcn_s_setprio(0);
      }
    }
  }

  if constexpr (REAL) {
#pragma unroll
    for (int r = 0; r < 16; ++r) {
      const float inv = 1.0f / accl[r];
      const int qr = qbase + (r & 3) + 8 * (r >> 2) + 4 * hh;
      float* op = Og + base + (size_t)qr * rowstride + q32;
      op[0]  = acc0[r] * inv;
      op[32] = acc1[r] * inv;
    }
  } else {
    float snk = sinkf + (float)usink;
    if constexpr (!DO_QKT) {  // stage-only: LDS readback keeps stores live
      asm volatile("" ::: "memory");
      snk += (float)Klds[0][tid & 127][0] + (float)Vtld[0][tid & 63][0];
    }
    if constexpr (DO_PV) {
#pragma unroll
      for (int r = 0; r < 16; ++r) snk += acc0[r] + acc1[r] + accl[r];
    }
    asm volatile("" :: "v"(snk));
    Og[(size_t)wg * 256 + tid] = snk;
  }
}

extern "C" void kernel_launch(void* const* d_in, const int* in_sizes, int n_in,
                              void* d_out, int out_size, void* d_ws, size_t ws_size,
                              hipStream_t stream) {
  const float* Q = (const float*)d_in[0];
  const float* K = (const float*)d_in[1];
  const float* V = (const float*)d_in[2];
  float* O  = (float*)d_out;
  float* ws = (float*)d_ws;
  dim3 g(512), blk(256);
  // probes (dispatch order = _ord): stage | stage+qkt | stage+qkt+sm | nostage-full
  hipLaunchKernelGGL((attn_k<1,  false>), g, blk, 0, stream, Q, K, V, ws);
  hipLaunchKernelGGL((attn_k<3,  false>), g, blk, 0, stream, Q, K, V, ws + 131072);
  hipLaunchKernelGGL((attn_k<7,  false>), g, blk, 0, stream, Q, K, V, ws + 262144);
  hipLaunchKernelGGL((attn_k<14, false>), g, blk, 0, stream, Q, K, V, ws + 393216);
  // real kernel (R12-identical math) -> d_out
  hipLaunchKernelGGL((attn_k<15, true>),  g, blk, 0, stream, Q, K, V, O);
}

// Round 15
// 137.539 us; speedup vs baseline: 1.4237x; 1.4237x over previous
//
#include <hip/hip_runtime.h>
#include <hip/hip_bf16.h>
#include <math.h>

// AnomalyAttention: causal MHA forward. KV-halved chains.
// Q,K,V: [B=4, L=2048, H=8, E=64] fp32; O: [B,L,H,E] fp32.
//
// Evidence (R4/R6/R10/R12): runtime ~= serial kv-chain length of the critical
// q-block x 1.78us per 64 kv rows, invariant to occupancy/staging/barriers.
// Fix: q-blocks 8..15 (128 rows each) split into lower/upper kv halves
// handled by two WGs (chain <= 16 tiles-of-64 everywhere); no-max exp2
// softmax (scale-invariant) makes the halves exactly additive. Split WGs
// write coalesced fp32 partials (LDS-transposed); a small reduce kernel
// sums pairs and divides. 768 WGs, all co-resident (LDS 36.9KB, VGPR<=128).
// Main loop body = R10-verified 32x32 MFMA structure (swapped QK^T,
// lane-local P, cvt_pk + v_permlane32_swap, ones-B row-sum, XOR swizzle,
// reg-prefetch double-buffer, one barrier per tile).

constexpr int Bn = 4, Ln = 2048, Hn = 8, En = 64;
constexpr int KVBLK = 64;

using f32x4  = __attribute__((ext_vector_type(4))) float;
using f32x16 = __attribute__((ext_vector_type(16))) float;
using bf16x8 = __attribute__((ext_vector_type(8))) short;
using u32x4  = __attribute__((ext_vector_type(4))) unsigned int;

#define SCALE_LOG2E 0.1803368801111204f

__device__ inline short2 cvt2(float a, float b) {
  __hip_bfloat162 h = __float22bfloat162_rn(make_float2(a, b));  // v_cvt_pk_bf16_f32
  return *reinterpret_cast<short2*>(&h);
}

__device__ inline unsigned pack2(float a, float b) {
  short2 s = cvt2(a, b);
  return *reinterpret_cast<unsigned*>(&s);
}

__device__ inline bf16x8 cvt8(f32x4 a, f32x4 b) {
  short2 p0 = cvt2(a[0], a[1]), p1 = cvt2(a[2], a[3]);
  short2 p2 = cvt2(b[0], b[1]), p3 = cvt2(b[2], b[3]);
  bf16x8 v;
  v[0] = p0.x; v[1] = p0.y; v[2] = p1.x; v[3] = p1.y;
  v[4] = p2.x; v[5] = p2.y; v[6] = p3.x; v[7] = p3.y;
  return v;
}

__global__ __launch_bounds__(256, 4)
void attn_part(const float* __restrict__ Qg, const float* __restrict__ Kg,
               const float* __restrict__ Vg, float* __restrict__ Og,
               float* __restrict__ ws) {
  const int wg = blockIdx.x;         // 0..767
  const int bh = wg & 31;
  const int s  = wg >> 5;            // 0..23
  int qb, t0, t1, half;
  bool split;
  if (s < 8) {                       // unsplit blocks qb 0..7
    split = false; half = 0;
    qb = s; t0 = 0; t1 = 2 * qb + 2;
  } else {                           // split blocks qb 8..15: kv halves
    split = true;
    const int ss = s - 8;
    qb = 8 + (ss >> 1);
    half = ss & 1;
    const int T = 2 * qb + 2;        // even
    t0 = half ? (T >> 1) : 0;
    t1 = half ? T : (T >> 1);
  }
  const int b    = bh >> 3;
  const int h    = bh & 7;
  const int tid  = threadIdx.x;
  const int lane = tid & 63;
  const int wave = tid >> 6;         // 0..3
  const int q32  = lane & 31;
  const int hh   = lane >> 5;        // 0..1

  // smem: staging (Klds+Vtld, 36864B) reused at the end as red/lred
  __shared__ __align__(16) char smem[36864];
  short (*Klds)[64][72] = reinterpret_cast<short(*)[64][72]>(smem);
  short (*Vtld)[64][72] = reinterpret_cast<short(*)[64][72]>(smem + 18432);

  const size_t base = ((size_t)b * Ln * Hn + (size_t)h) * En;
  const int rowstride = Hn * En;  // 512
  const int qbase = qb * 128 + wave * 32;
  const int q     = qbase + q32;

  // Q B-frags pre-scaled into exp2 domain: lane holds Q[q][16m + 8hh + j]
  bf16x8 qf[4];
  {
    const float* qp = Qg + base + (size_t)q * rowstride + hh * 8;
#pragma unroll
    for (int m = 0; m < 4; ++m) {
      f32x4 a = *(const f32x4*)(qp + 16 * m);
      f32x4 c = *(const f32x4*)(qp + 16 * m + 4);
#pragma unroll
      for (int i = 0; i < 4; ++i) { a[i] *= SCALE_LOG2E; c[i] *= SCALE_LOG2E; }
      qf[m] = cvt8(a, c);
    }
  }

#define ZERO16 {0.f,0.f,0.f,0.f,0.f,0.f,0.f,0.f,0.f,0.f,0.f,0.f,0.f,0.f,0.f,0.f}
  f32x16 acc0 = ZERO16, acc1 = ZERO16, accl = ZERO16;
  const short oneb = (short)0x3F80;
  const bf16x8 ones = {oneb, oneb, oneb, oneb, oneb, oneb, oneb, oneb};

  // K staging: rows kr, kr+32; cols kc..kc+7 (R10-verified)
  const int kr = tid >> 3;            // 0..31
  const int kc = (tid & 7) << 3;      // 0..56
  const int ksw1 = ((kr >> 3) & 7) << 3;
  const int ksw2 = (((kr >> 3) + 4) & 7) << 3;
  // V staging: kv rows (vkv, vkv+1), d cols vdd..vdd+7 (transposed write)
  const int vkv = (tid & 31) << 1;    // 0..62
  const int vdd = (tid >> 5) << 3;    // 0..56
  const int vsw = ((vdd >> 3) & 7) << 3;

  const float* kbase = Kg + base;
  const float* vbase = Vg + base;

  f32x4 ka0, ka1, kb0, kb1, vl0, vl1, vh0, vh1;

#define LOAD_TILE(TB)                                                   \
  {                                                                     \
    const float* kp = kbase + (size_t)((TB) + kr) * rowstride + kc;     \
    ka0 = *(const f32x4*)kp;  ka1 = *(const f32x4*)(kp + 4);            \
    const float* kp2 = kp + 32 * rowstride;                             \
    kb0 = *(const f32x4*)kp2; kb1 = *(const f32x4*)(kp2 + 4);           \
    const float* vp = vbase + (size_t)((TB) + vkv) * rowstride + vdd;   \
    vl0 = *(const f32x4*)vp;  vl1 = *(const f32x4*)(vp + 4);            \
    const float* vp2 = vp + rowstride;                                  \
    vh0 = *(const f32x4*)vp2; vh1 = *(const f32x4*)(vp2 + 4);           \
  }

#define WRITE_TILE(BUF)                                                 \
  {                                                                     \
    *(bf16x8*)&Klds[BUF][kr][kc ^ ksw1]      = cvt8(ka0, ka1);          \
    *(bf16x8*)&Klds[BUF][kr + 32][kc ^ ksw2] = cvt8(kb0, kb1);          \
    _Pragma("unroll")                                                   \
    for (int i = 0; i < 4; ++i)                                         \
      *(unsigned*)&Vtld[BUF][vdd + i][vkv ^ vsw] = pack2(vl0[i], vh0[i]); \
    _Pragma("unroll")                                                   \
    for (int i = 0; i < 4; ++i)                                         \
      *(unsigned*)&Vtld[BUF][vdd + 4 + i][vkv ^ vsw] = pack2(vl1[i], vh1[i]); \
  }

  // prologue
  LOAD_TILE(t0 * KVBLK)
  WRITE_TILE(0)
  if (t0 + 1 < t1) LOAD_TILE((t0 + 1) * KVBLK)

  for (int t = t0; t < t1; ++t) {
    const int cur = (t - t0) & 1;
    __syncthreads();  // buf[cur] staged; prev readers of buf[cur^1] done
    if (t + 1 < t1) {
      WRITE_TILE(cur ^ 1)
      if (t + 2 < t1) LOAD_TILE((t + 2) * KVBLK)
    }

    const int tb = t * KVBLK;
    if (tb > qbase + 31) continue;  // fully masked for this wave (wave-uniform)

    const bool diag = (tb + KVBLK - 1 > qbase);

    bf16x8 pa[4];  // P A-frags, kv chunks of 16
#pragma unroll
    for (int sub = 0; sub < 2; ++sub) {
      const int krow = sub * 32 + q32;
      const int ksw  = ((krow >> 3) & 7) << 3;
      f32x16 sv = ZERO16;
      __builtin_amdgcn_s_setprio(1);
#pragma unroll
      for (int m = 0; m < 4; ++m) {
        bf16x8 kf = *(const bf16x8*)&Klds[cur][krow][(m * 16 + hh * 8) ^ ksw];
        sv = __builtin_amdgcn_mfma_f32_32x32x16_bf16(kf, qf[m], sv, 0, 0, 0);
      }
      __builtin_amdgcn_s_setprio(0);
      if (diag) {
#pragma unroll
        for (int r = 0; r < 16; ++r) {
          const int kv = tb + sub * 32 + (r & 3) + 8 * (r >> 2) + 4 * hh;
          sv[r] = (kv > q) ? 0.f : exp2f(sv[r]);
        }
      } else {
#pragma unroll
        for (int r = 0; r < 16; ++r) sv[r] = exp2f(sv[r]);
      }
      unsigned w0 = pack2(sv[0], sv[1]),   w1 = pack2(sv[2], sv[3]);
      unsigned w2 = pack2(sv[4], sv[5]),   w3 = pack2(sv[6], sv[7]);
      unsigned w4 = pack2(sv[8], sv[9]),   w5 = pack2(sv[10], sv[11]);
      unsigned w6 = pack2(sv[12], sv[13]), w7 = pack2(sv[14], sv[15]);
      asm("v_permlane32_swap_b32 %0, %1" : "+v"(w0), "+v"(w2));
      asm("v_permlane32_swap_b32 %0, %1" : "+v"(w1), "+v"(w3));
      asm("v_permlane32_swap_b32 %0, %1" : "+v"(w4), "+v"(w6));
      asm("v_permlane32_swap_b32 %0, %1" : "+v"(w5), "+v"(w7));
      u32x4 Wa = {w0, w1, w2, w3};
      u32x4 Wb = {w4, w5, w6, w7};
      pa[2 * sub + 0] = __builtin_bit_cast(bf16x8, Wa);
      pa[2 * sub + 1] = __builtin_bit_cast(bf16x8, Wb);
    }

    const int vswA = ((q32 >> 3) & 7) << 3;
    const int vswB = (((q32 >> 3) + 4) & 7) << 3;
    __builtin_amdgcn_s_setprio(1);
#pragma unroll
    for (int m = 0; m < 4; ++m) {
      bf16x8 vf0 = *(const bf16x8*)&Vtld[cur][q32][(m * 16 + hh * 8) ^ vswA];
      acc0 = __builtin_amdgcn_mfma_f32_32x32x16_bf16(pa[m], vf0, acc0, 0, 0, 0);
      bf16x8 vf1 = *(const bf16x8*)&Vtld[cur][q32 + 32][(m * 16 + hh * 8) ^ vswB];
      acc1 = __builtin_amdgcn_mfma_f32_32x32x16_bf16(pa[m], vf1, acc1, 0, 0, 0);
      accl = __builtin_amdgcn_mfma_f32_32x32x16_bf16(pa[m], ones, accl, 0, 0, 0);
    }
    __builtin_amdgcn_s_setprio(0);
  }

  if (!split) {
    // direct epilogue: reg r -> q row qbase+(r&3)+8*(r>>2)+4hh; col d = q32 (+32)
#pragma unroll
    for (int r = 0; r < 16; ++r) {
      const float inv = 1.0f / accl[r];
      const int qr = qbase + (r & 3) + 8 * (r >> 2) + 4 * hh;
      float* op = Og + base + (size_t)qr * rowstride + q32;
      op[0]  = acc0[r] * inv;
      op[32] = acc1[r] * inv;
    }
  } else {
    // partial epilogue: LDS-transpose then coalesced store to ws
    __syncthreads();  // all staging-LDS readers done; safe to alias
    float* red  = (float*)smem;           // [128][64]
    float* lred = (float*)(smem + 32768); // [128]
#pragma unroll
    for (int r = 0; r < 16; ++r) {
      const int row = wave * 32 + (r & 3) + 8 * (r >> 2) + 4 * hh;
      red[row * 64 + q32]      = acc0[r];
      red[row * 64 + 32 + q32] = acc1[r];
      if (q32 == 0) lred[row] = accl[r];
    }
    __syncthreads();
    const int slot = ((bh * 8 + (qb - 8)) * 2 + half);
    float* W = ws + (size_t)slot * 8320;  // 8192 num + 128 l
#pragma unroll
    for (int j = 0; j < 8; ++j) {
      const int idx = j * 1024 + tid * 4;
      *(f32x4*)(W + idx) = *(const f32x4*)(red + idx);
    }
    if (tid < 128) W[8192 + tid] = lred[tid];
  }
}

__global__ __launch_bounds__(256)
void attn_reduce(const float* __restrict__ ws, float* __restrict__ Og) {
  const int blk = blockIdx.x;        // 0..255 = bh*8 + (qb-8)
  const int bh  = blk >> 3;
  const int qb  = 8 + (blk & 7);
  const int b   = bh >> 3;
  const int h   = bh & 7;
  const int tid = threadIdx.x;

  const float* p0 = ws + (size_t)(blk * 2) * 8320;
  const float* p1 = p0 + 8320;
  const size_t base = ((size_t)b * Ln * Hn + (size_t)h) * En;

#pragma unroll
  for (int j = 0; j < 8; ++j) {
    const int idx = j * 1024 + tid * 4;
    const int row = idx >> 6;
    const int d   = idx & 63;
    f32x4 n0 = *(const f32x4*)(p0 + idx);
    f32x4 n1 = *(const f32x4*)(p1 + idx);
    const float inv = 1.0f / (p0[8192 + row] + p1[8192 + row]);
    f32x4 o;
#pragma unroll
    for (int k = 0; k < 4; ++k) o[k] = (n0[k] + n1[k]) * inv;
    float* op = Og + base + (size_t)(qb * 128 + row) * (Hn * En) + d;
    *(f32x4*)op = o;
  }
}

extern "C" void kernel_launch(void* const* d_in, const int* in_sizes, int n_in,
                              void* d_out, int out_size, void* d_ws, size_t ws_size,
                              hipStream_t stream) {
  const float* Q = (const float*)d_in[0];
  const float* K = (const float*)d_in[1];
  const float* V = (const float*)d_in[2];
  float* O  = (float*)d_out;
  float* ws = (float*)d_ws;  // 512 slots x 8320 floats = 17.0 MB
  hipLaunchKernelGGL(attn_part,   dim3(768), dim3(256), 0, stream, Q, K, V, O, ws);
  hipLaunchKernelGGL(attn_reduce, dim3(256), dim3(256), 0, stream, ws, O);
}

// Round 16
// 58.133 us; speedup vs baseline: 3.3684x; 2.3660x over previous
//
#include <hip/hip_runtime.h>
#include <hip/hip_bf16.h>
#include <math.h>

// AnomalyAttention: causal MHA forward. KV-halved chains (clean retest).
// Q,K,V: [B=4, L=2048, H=8, E=64] fp32; O: [B,L,H,E] fp32.
//
// R15 post-mortem: __launch_bounds__(256,4) capped VGPR at 64 -> spills
// (111MB scratch writes). This round: identical structure with (256,2)
// (VGPR ~116, R12-verified no-spill) + LPT chain ordering.
// Max serial kv-chain = 16 tiles-of-64 = 1024 rows (half of R12's 2048).
// No-max exp2 softmax (scale-invariant) -> kv-halves exactly additive;
// split blocks write coalesced fp32 partials, reduce kernel sums+divides.
// Body = R10-verified 32x32 MFMA structure.

constexpr int Bn = 4, Ln = 2048, Hn = 8, En = 64;
constexpr int KVBLK = 64;

using f32x4  = __attribute__((ext_vector_type(4))) float;
using f32x16 = __attribute__((ext_vector_type(16))) float;
using bf16x8 = __attribute__((ext_vector_type(8))) short;
using u32x4  = __attribute__((ext_vector_type(4))) unsigned int;

#define SCALE_LOG2E 0.1803368801111204f

__device__ inline short2 cvt2(float a, float b) {
  __hip_bfloat162 h = __float22bfloat162_rn(make_float2(a, b));  // v_cvt_pk_bf16_f32
  return *reinterpret_cast<short2*>(&h);
}

__device__ inline unsigned pack2(float a, float b) {
  short2 s = cvt2(a, b);
  return *reinterpret_cast<unsigned*>(&s);
}

__device__ inline bf16x8 cvt8(f32x4 a, f32x4 b) {
  short2 p0 = cvt2(a[0], a[1]), p1 = cvt2(a[2], a[3]);
  short2 p2 = cvt2(b[0], b[1]), p3 = cvt2(b[2], b[3]);
  bf16x8 v;
  v[0] = p0.x; v[1] = p0.y; v[2] = p1.x; v[3] = p1.y;
  v[4] = p2.x; v[5] = p2.y; v[6] = p3.x; v[7] = p3.y;
  return v;
}

__global__ __launch_bounds__(256, 2)
void attn_part(const float* __restrict__ Qg, const float* __restrict__ Kg,
               const float* __restrict__ Vg, float* __restrict__ Og,
               float* __restrict__ ws) {
  // LPT: chain slices sorted by descending tile count
  static const __device__ int ord[24] = {7, 22, 23, 20, 21, 6, 18, 19, 16, 17,
                                         5, 14, 15, 12, 13, 4, 10, 11, 8, 9,
                                         3, 2, 1, 0};
  const int wg = blockIdx.x;         // 0..767
  const int bh = wg & 31;
  const int s  = ord[wg >> 5];       // 0..23
  int qb, t0, t1, half;
  bool split;
  if (s < 8) {                       // unsplit blocks qb 0..7
    split = false; half = 0;
    qb = s; t0 = 0; t1 = 2 * qb + 2;
  } else {                           // split blocks qb 8..15: kv halves
    split = true;
    const int ss = s - 8;
    qb = 8 + (ss >> 1);
    half = ss & 1;
    const int T = 2 * qb + 2;        // even
    t0 = half ? (T >> 1) : 0;
    t1 = half ? T : (T >> 1);
  }
  const int b    = bh >> 3;
  const int h    = bh & 7;
  const int tid  = threadIdx.x;
  const int lane = tid & 63;
  const int wave = tid >> 6;         // 0..3
  const int q32  = lane & 31;
  const int hh   = lane >> 5;        // 0..1

  // smem: staging (Klds+Vtld) reused at the end as red/lred
  __shared__ __align__(16) char smem[36864];
  short (*Klds)[64][72] = reinterpret_cast<short(*)[64][72]>(smem);
  short (*Vtld)[64][72] = reinterpret_cast<short(*)[64][72]>(smem + 18432);

  const size_t base = ((size_t)b * Ln * Hn + (size_t)h) * En;
  const int rowstride = Hn * En;  // 512
  const int qbase = qb * 128 + wave * 32;
  const int q     = qbase + q32;

  // Q B-frags pre-scaled into exp2 domain: lane holds Q[q][16m + 8hh + j]
  bf16x8 qf[4];
  {
    const float* qp = Qg + base + (size_t)q * rowstride + hh * 8;
#pragma unroll
    for (int m = 0; m < 4; ++m) {
      f32x4 a = *(const f32x4*)(qp + 16 * m);
      f32x4 c = *(const f32x4*)(qp + 16 * m + 4);
#pragma unroll
      for (int i = 0; i < 4; ++i) { a[i] *= SCALE_LOG2E; c[i] *= SCALE_LOG2E; }
      qf[m] = cvt8(a, c);
    }
  }

#define ZERO16 {0.f,0.f,0.f,0.f,0.f,0.f,0.f,0.f,0.f,0.f,0.f,0.f,0.f,0.f,0.f,0.f}
  f32x16 acc0 = ZERO16, acc1 = ZERO16, accl = ZERO16;
  const short oneb = (short)0x3F80;
  const bf16x8 ones = {oneb, oneb, oneb, oneb, oneb, oneb, oneb, oneb};

  // K staging: rows kr, kr+32; cols kc..kc+7 (R10-verified)
  const int kr = tid >> 3;            // 0..31
  const int kc = (tid & 7) << 3;      // 0..56
  const int ksw1 = ((kr >> 3) & 7) << 3;
  const int ksw2 = (((kr >> 3) + 4) & 7) << 3;
  // V staging: kv rows (vkv, vkv+1), d cols vdd..vdd+7 (transposed write)
  const int vkv = (tid & 31) << 1;    // 0..62
  const int vdd = (tid >> 5) << 3;    // 0..56
  const int vsw = ((vdd >> 3) & 7) << 3;

  const float* kbase = Kg + base;
  const float* vbase = Vg + base;

  f32x4 ka0, ka1, kb0, kb1, vl0, vl1, vh0, vh1;

#define LOAD_TILE(TB)                                                   \
  {                                                                     \
    const float* kp = kbase + (size_t)((TB) + kr) * rowstride + kc;     \
    ka0 = *(const f32x4*)kp;  ka1 = *(const f32x4*)(kp + 4);            \
    const float* kp2 = kp + 32 * rowstride;                             \
    kb0 = *(const f32x4*)kp2; kb1 = *(const f32x4*)(kp2 + 4);           \
    const float* vp = vbase + (size_t)((TB) + vkv) * rowstride + vdd;   \
    vl0 = *(const f32x4*)vp;  vl1 = *(const f32x4*)(vp + 4);            \
    const float* vp2 = vp + rowstride;                                  \
    vh0 = *(const f32x4*)vp2; vh1 = *(const f32x4*)(vp2 + 4);           \
  }

#define WRITE_TILE(BUF)                                                 \
  {                                                                     \
    *(bf16x8*)&Klds[BUF][kr][kc ^ ksw1]      = cvt8(ka0, ka1);          \
    *(bf16x8*)&Klds[BUF][kr + 32][kc ^ ksw2] = cvt8(kb0, kb1);          \
    _Pragma("unroll")                                                   \
    for (int i = 0; i < 4; ++i)                                         \
      *(unsigned*)&Vtld[BUF][vdd + i][vkv ^ vsw] = pack2(vl0[i], vh0[i]); \
    _Pragma("unroll")                                                   \
    for (int i = 0; i < 4; ++i)                                         \
      *(unsigned*)&Vtld[BUF][vdd + 4 + i][vkv ^ vsw] = pack2(vl1[i], vh1[i]); \
  }

  // prologue
  LOAD_TILE(t0 * KVBLK)
  WRITE_TILE(0)
  if (t0 + 1 < t1) LOAD_TILE((t0 + 1) * KVBLK)

  for (int t = t0; t < t1; ++t) {
    const int cur = (t - t0) & 1;
    __syncthreads();  // buf[cur] staged; prev readers of buf[cur^1] done
    if (t + 1 < t1) {
      WRITE_TILE(cur ^ 1)
      if (t + 2 < t1) LOAD_TILE((t + 2) * KVBLK)
    }

    const int tb = t * KVBLK;
    if (tb > qbase + 31) continue;  // fully masked for this wave (wave-uniform)

    const bool diag = (tb + KVBLK - 1 > qbase);

    bf16x8 pa[4];  // P A-frags, kv chunks of 16
#pragma unroll
    for (int sub = 0; sub < 2; ++sub) {
      const int krow = sub * 32 + q32;
      const int ksw  = ((krow >> 3) & 7) << 3;
      f32x16 sv = ZERO16;
      __builtin_amdgcn_s_setprio(1);
#pragma unroll
      for (int m = 0; m < 4; ++m) {
        bf16x8 kf = *(const bf16x8*)&Klds[cur][krow][(m * 16 + hh * 8) ^ ksw];
        sv = __builtin_amdgcn_mfma_f32_32x32x16_bf16(kf, qf[m], sv, 0, 0, 0);
      }
      __builtin_amdgcn_s_setprio(0);
      if (diag) {
#pragma unroll
        for (int r = 0; r < 16; ++r) {
          const int kv = tb + sub * 32 + (r & 3) + 8 * (r >> 2) + 4 * hh;
          sv[r] = (kv > q) ? 0.f : exp2f(sv[r]);
        }
      } else {
#pragma unroll
        for (int r = 0; r < 16; ++r) sv[r] = exp2f(sv[r]);
      }
      unsigned w0 = pack2(sv[0], sv[1]),   w1 = pack2(sv[2], sv[3]);
      unsigned w2 = pack2(sv[4], sv[5]),   w3 = pack2(sv[6], sv[7]);
      unsigned w4 = pack2(sv[8], sv[9]),   w5 = pack2(sv[10], sv[11]);
      unsigned w6 = pack2(sv[12], sv[13]), w7 = pack2(sv[14], sv[15]);
      asm("v_permlane32_swap_b32 %0, %1" : "+v"(w0), "+v"(w2));
      asm("v_permlane32_swap_b32 %0, %1" : "+v"(w1), "+v"(w3));
      asm("v_permlane32_swap_b32 %0, %1" : "+v"(w4), "+v"(w6));
      asm("v_permlane32_swap_b32 %0, %1" : "+v"(w5), "+v"(w7));
      u32x4 Wa = {w0, w1, w2, w3};
      u32x4 Wb = {w4, w5, w6, w7};
      pa[2 * sub + 0] = __builtin_bit_cast(bf16x8, Wa);
      pa[2 * sub + 1] = __builtin_bit_cast(bf16x8, Wb);
    }

    const int vswA = ((q32 >> 3) & 7) << 3;
    const int vswB = (((q32 >> 3) + 4) & 7) << 3;
    __builtin_amdgcn_s_setprio(1);
#pragma unroll
    for (int m = 0; m < 4; ++m) {
      bf16x8 vf0 = *(const bf16x8*)&Vtld[cur][q32][(m * 16 + hh * 8) ^ vswA];
      acc0 = __builtin_amdgcn_mfma_f32_32x32x16_bf16(pa[m], vf0, acc0, 0, 0, 0);
      bf16x8 vf1 = *(const bf16x8*)&Vtld[cur][q32 + 32][(m * 16 + hh * 8) ^ vswB];
      acc1 = __builtin_amdgcn_mfma_f32_32x32x16_bf16(pa[m], vf1, acc1, 0, 0, 0);
      accl = __builtin_amdgcn_mfma_f32_32x32x16_bf16(pa[m], ones, accl, 0, 0, 0);
    }
    __builtin_amdgcn_s_setprio(0);
  }

  if (!split) {
    // direct epilogue: reg r -> q row qbase+(r&3)+8*(r>>2)+4hh; col d = q32 (+32)
#pragma unroll
    for (int r = 0; r < 16; ++r) {
      const float inv = 1.0f / accl[r];
      const int qr = qbase + (r & 3) + 8 * (r >> 2) + 4 * hh;
      float* op = Og + base + (size_t)qr * rowstride + q32;
      op[0]  = acc0[r] * inv;
      op[32] = acc1[r] * inv;
    }
  } else {
    // partial epilogue: LDS-transpose then coalesced store to ws
    __syncthreads();  // all staging-LDS readers done; safe to alias
    float* red  = (float*)smem;           // [128][64]
    float* lred = (float*)(smem + 32768); // [128]
#pragma unroll
    for (int r = 0; r < 16; ++r) {
      const int row = wave * 32 + (r & 3) + 8 * (r >> 2) + 4 * hh;
      red[row * 64 + q32]      = acc0[r];
      red[row * 64 + 32 + q32] = acc1[r];
      if (q32 == 0) lred[row] = accl[r];
    }
    __syncthreads();
    const int slot = ((bh * 8 + (qb - 8)) * 2 + half);
    float* W = ws + (size_t)slot * 8320;  // 8192 num + 128 l
#pragma unroll
    for (int j = 0; j < 8; ++j) {
      const int idx = j * 1024 + tid * 4;
      *(f32x4*)(W + idx) = *(const f32x4*)(red + idx);
    }
    if (tid < 128) W[8192 + tid] = lred[tid];
  }
}

__global__ __launch_bounds__(256)
void attn_reduce(const float* __restrict__ ws, float* __restrict__ Og) {
  const int blk = blockIdx.x;        // 0..255 = bh*8 + (qb-8)
  const int bh  = blk >> 3;
  const int qb  = 8 + (blk & 7);
  const int b   = bh >> 3;
  const int h   = bh & 7;
  const int tid = threadIdx.x;

  const float* p0 = ws + (size_t)(blk * 2) * 8320;
  const float* p1 = p0 + 8320;
  const size_t base = ((size_t)b * Ln * Hn + (size_t)h) * En;

#pragma unroll
  for (int j = 0; j < 8; ++j) {
    const int idx = j * 1024 + tid * 4;
    const int row = idx >> 6;
    const int d   = idx & 63;
    f32x4 n0 = *(const f32x4*)(p0 + idx);
    f32x4 n1 = *(const f32x4*)(p1 + idx);
    const float inv = 1.0f / (p0[8192 + row] + p1[8192 + row]);
    f32x4 o;
#pragma unroll
    for (int k = 0; k < 4; ++k) o[k] = (n0[k] + n1[k]) * inv;
    float* op = Og + base + (size_t)(qb * 128 + row) * (Hn * En) + d;
    *(f32x4*)op = o;
  }
}

extern "C" void kernel_launch(void* const* d_in, const int* in_sizes, int n_in,
                              void* d_out, int out_size, void* d_ws, size_t ws_size,
                              hipStream_t stream) {
  const float* Q = (const float*)d_in[0];
  const float* K = (const float*)d_in[1];
  const float* V = (const float*)d_in[2];
  float* O  = (float*)d_out;
  float* ws = (float*)d_ws;  // 512 slots x 8320 floats = 17.0 MB
  hipLaunchKernelGGL(attn_part,   dim3(768), dim3(256), 0, stream, Q, K, V, O, ws);
  hipLaunchKernelGGL(attn_reduce, dim3(256), dim3(256), 0, stream, ws, O);
}